// Round 5
// baseline (154.481 us; speedup 1.0000x reference)
//
#include <hip/hip_runtime.h>

#define MARGIN 0.3f

typedef __attribute__((ext_vector_type(8))) short short8;
typedef __attribute__((ext_vector_type(4))) short short4v;
typedef __attribute__((ext_vector_type(4))) float floatx4;

// ---- helpers ----------------------------------------------------------------

// order-preserving float->uint encoding so unsigned atomicMin == float min
__device__ __forceinline__ unsigned enc_f32(float f) {
    unsigned u = __float_as_uint(f);
    return (u & 0x80000000u) ? ~u : (u | 0x80000000u);
}
__device__ __forceinline__ float dec_f32(unsigned u) {
    return (u & 0x80000000u) ? __uint_as_float(u & 0x7fffffffu)
                             : __uint_as_float(~u);
}
// fp32 -> bf16 bits, round-to-nearest-even
__device__ __forceinline__ short f2bf(float f) {
    unsigned u = __float_as_uint(f);
    u = u + 0x7fffu + ((u >> 16) & 1u);
    return (short)(u >> 16);
}

// ---- kernel 1: prepass ------------------------------------------------------
// Plain row-major fp32 -> bf16 (MFMA fragments are 16B/lane contiguous in this
// layout, so no swizzle needed). Also sq2 (exact fp32), rowmin/cnt/out init.
__global__ void prep_kernel(const float* __restrict__ z1, const float* __restrict__ z2,
                            short* __restrict__ z1b, short* __restrict__ z2b,
                            float* __restrict__ sq2, unsigned* __restrict__ rowmin,
                            unsigned* __restrict__ cnt, float* __restrict__ out) {
    int idx = blockIdx.x * 256 + threadIdx.x;   // float4 index, 32 per row
    float4 fa = ((const float4*)z1)[idx];
    float4 fb = ((const float4*)z2)[idx];
    short4v sa = { f2bf(fa.x), f2bf(fa.y), f2bf(fa.z), f2bf(fa.w) };
    short4v sb = { f2bf(fb.x), f2bf(fb.y), f2bf(fb.z), f2bf(fb.w) };
    ((short4v*)z1b)[idx] = sa;                  // contiguous 8B stores
    ((short4v*)z2b)[idx] = sb;
    float s = fb.x * fb.x + fb.y * fb.y + fb.z * fb.z + fb.w * fb.w;
    #pragma unroll
    for (int m = 16; m >= 1; m >>= 1) s += __shfl_xor(s, m);
    if ((idx & 31) == 0) sq2[idx >> 5] = s;
    if (threadIdx.x < 8) rowmin[blockIdx.x * 8 + threadIdx.x] = 0xFFFFFFFFu;
    if (blockIdx.x == 0) {
        if (threadIdx.x < 32) cnt[threadIdx.x] = 0u;
        if (threadIdx.x == 0) out[0] = 0.0f;
    }
}

// ---- kernel 2: barrier-free register GEMM + row-min + fused loss ------------
// grid (16, 32): rg = 256-row group (4 waves x 64 rows), cg = 512-col group
// (16 tiles of 32 cols). 512 blocks = 2/CU. NO LDS staging, NO barriers in the
// main loop: A frags persistent in VGPRs, B frags loaded global->VGPR with a
// register double-buffer; compiler interleaves MFMA with vmcnt waits.
__global__ __launch_bounds__(256, 2)
void gemm_min_kernel(const short* __restrict__ z1b, const short* __restrict__ z2b,
                     const float* __restrict__ sq2,
                     const float* __restrict__ z1, const float* __restrict__ z2,
                     unsigned* __restrict__ rowmin, unsigned* __restrict__ cnt,
                     float* __restrict__ out, int n)
{
    __shared__ float shmin[256];
    __shared__ float lsum[4];
    __shared__ int   fin_s;

    const int rg = blockIdx.y, cg = blockIdx.x;
    const int tid = threadIdx.x, w = tid >> 6, lane = tid & 63;
    const int quad = lane >> 4, l15 = lane & 15;
    const int rowbase = rg * 256 + w * 64;      // this wave's 64 rows
    const int colorig = cg * 512;

    // hoist A fragments: lane holds A[m = rowbase+sm*16+l15][k = kk*32+quad*8 ..+7]
    short8 af[4][4];
    #pragma unroll
    for (int sm = 0; sm < 4; ++sm) {
        const short* pa = z1b + (size_t)(rowbase + sm * 16 + l15) * 128 + quad * 8;
        #pragma unroll
        for (int kk = 0; kk < 4; ++kk)
            af[sm][kk] = *(const short8*)(pa + kk * 32);
    }

    float vmin[4][4];
    #pragma unroll
    for (int sm = 0; sm < 4; ++sm)
        #pragma unroll
        for (int reg = 0; reg < 4; ++reg)
            vmin[sm][reg] = 3.0e38f;

    // B fragment register double-buffer: [buf][sn][kk]
    short8 bfb[2][2][4];
    #pragma unroll
    for (int sn = 0; sn < 2; ++sn) {
        const short* pb = z2b + (size_t)(colorig + sn * 16 + l15) * 128 + quad * 8;
        #pragma unroll
        for (int kk = 0; kk < 4; ++kk)
            bfb[0][sn][kk] = *(const short8*)(pb + kk * 32);
    }

    #pragma unroll
    for (int t = 0; t < 16; ++t) {
        const int colbase = colorig + t * 32;
        if (t < 15) {                           // prefetch next tile's B frags
            const int cn = colbase + 32;
            #pragma unroll
            for (int sn = 0; sn < 2; ++sn) {
                const short* pb = z2b + (size_t)(cn + sn * 16 + l15) * 128 + quad * 8;
                #pragma unroll
                for (int kk = 0; kk < 4; ++kk)
                    bfb[(t + 1) & 1][sn][kk] = *(const short8*)(pb + kk * 32);
            }
        }
        float s2v[2];
        s2v[0] = sq2[colbase + l15];
        s2v[1] = sq2[colbase + 16 + l15];

        floatx4 acc[4][2];
        #pragma unroll
        for (int sm = 0; sm < 4; ++sm)
            #pragma unroll
            for (int sn = 0; sn < 2; ++sn)
                acc[sm][sn] = (floatx4)0.0f;

        #pragma unroll
        for (int kk = 0; kk < 4; ++kk)
            #pragma unroll
            for (int sm = 0; sm < 4; ++sm)
                #pragma unroll
                for (int sn = 0; sn < 2; ++sn)
                    acc[sm][sn] = __builtin_amdgcn_mfma_f32_16x16x32_bf16(
                        af[sm][kk], bfb[t & 1][sn][kk], acc[sm][sn], 0, 0, 0);

        // fold row-min; diagonal mask only in the one overlapping tile
        if (((colbase >> 6) << 6) == rowbase) {   // wave-uniform branch
            #pragma unroll
            for (int sm = 0; sm < 4; ++sm)
                #pragma unroll
                for (int reg = 0; reg < 4; ++reg) {
                    int gi = rowbase + sm * 16 + quad * 4 + reg;
                    #pragma unroll
                    for (int sn = 0; sn < 2; ++sn) {
                        int gj = colbase + sn * 16 + l15;
                        float v = fmaf(-2.0f, acc[sm][sn][reg], s2v[sn]);
                        v = (gi == gj) ? 3.0e38f : v;
                        vmin[sm][reg] = fminf(vmin[sm][reg], v);
                    }
                }
        } else {
            #pragma unroll
            for (int sm = 0; sm < 4; ++sm)
                #pragma unroll
                for (int reg = 0; reg < 4; ++reg) {
                    float v0 = fmaf(-2.0f, acc[sm][0][reg], s2v[0]);
                    float v1 = fmaf(-2.0f, acc[sm][1][reg], s2v[1]);
                    vmin[sm][reg] = fminf(vmin[sm][reg], fminf(v0, v1));
                }
        }
    }

    // min across the 16 lanes of each quad, one atomicMin per row
    #pragma unroll
    for (int sm = 0; sm < 4; ++sm)
        #pragma unroll
        for (int reg = 0; reg < 4; ++reg) {
            float vm = vmin[sm][reg];
            #pragma unroll
            for (int m = 8; m >= 1; m >>= 1)
                vm = fminf(vm, __shfl_xor(vm, m));
            if (l15 == 0)
                atomicMin(&rowmin[rowbase + sm * 16 + quad * 4 + reg], enc_f32(vm));
        }

    __syncthreads();
    if (tid == 0) {
        __threadfence();    // release: this block's mins visible before bump
        fin_s = (atomicAdd(&cnt[rg], 1u) == 15u);
    }
    __syncthreads();
    if (!fin_s) return;
    __threadfence();        // acquire: see all 16 blocks' mins

    // fused loss for rows [rg*256, rg*256+256): exact fp32 pos-dist
    {
        unsigned rm = atomicMin(&rowmin[rg * 256 + tid], 0xFFFFFFFFu);  // forced read
        shmin[tid] = dec_f32(rm);
    }
    __syncthreads();

    float acc_loss = 0.0f;
    for (int k = 0; k < 64; ++k) {              // wave w: rows w*64 .. w*64+63
        int r = w * 64 + k;
        int i = rg * 256 + r;
        const float* p1 = z1 + (size_t)i * 128;
        const float* p2 = z2 + (size_t)i * 128;
        float a0 = p1[lane], a1 = p1[lane + 64];
        float b0 = p2[lane], b1 = p2[lane + 64];
        float d0 = a0 - b0, d1 = a1 - b1;
        float pos2 = d0 * d0 + d1 * d1;
        float s1   = a0 * a0 + a1 * a1;
        #pragma unroll
        for (int m = 32; m >= 1; m >>= 1) {
            pos2 += __shfl_xor(pos2, m);
            s1   += __shfl_xor(s1, m);
        }
        if (lane == 0) {
            float neg2 = s1 + shmin[r];
            float hard = sqrtf(fmaxf(neg2, 0.0f));
            float pos  = sqrtf(fmaxf(pos2, 0.0f));
            acc_loss += fmaxf(pos - hard + MARGIN, 0.0f);
        }
    }
    if (lane == 0) lsum[w] = acc_loss;
    __syncthreads();
    if (tid == 0)
        atomicAdd(out, (lsum[0] + lsum[1] + lsum[2] + lsum[3]) / (float)n);
}

// ---- launch -----------------------------------------------------------------
extern "C" void kernel_launch(void* const* d_in, const int* in_sizes, int n_in,
                              void* d_out, int out_size, void* d_ws, size_t ws_size,
                              hipStream_t stream) {
    const float* z1 = (const float*)d_in[0];
    const float* z2 = (const float*)d_in[1];
    const int n = in_sizes[0] / 128;            // 8192

    char* ws = (char*)d_ws;
    short*    z1b    = (short*)ws;                                   // 2 MB
    short*    z2b    = (short*)(ws + (size_t)n * 128 * 2);           // 2 MB
    float*    sq2    = (float*)(ws + (size_t)n * 128 * 4);           // 32 KB
    unsigned* rowmin = (unsigned*)(ws + (size_t)n * 128 * 4 + n * 4);// 32 KB
    unsigned* cnt    = (unsigned*)(ws + (size_t)n * 128 * 4 + n * 8);// 128 B
    float*    out    = (float*)d_out;

    prep_kernel<<<n * 32 / 256, 256, 0, stream>>>(z1, z2, z1b, z2b, sq2,
                                                  rowmin, cnt, out);
    dim3 grid(16, n / 256);                     // (colgroups, rowgroups)
    gemm_min_kernel<<<grid, 256, 0, stream>>>(z1b, z2b, sq2, z1, z2,
                                              rowmin, cnt, out, n);
}

// Round 7
// 102.251 us; speedup vs baseline: 1.5108x; 1.5108x over previous
//
#include <hip/hip_runtime.h>

#define MARGIN 0.3f

typedef __attribute__((ext_vector_type(8))) short short8;
typedef __attribute__((ext_vector_type(4))) float floatx4;

// ---- helpers ----------------------------------------------------------------

// order-preserving float->uint encoding so unsigned atomicMin == float min
__device__ __forceinline__ unsigned enc_f32(float f) {
    unsigned u = __float_as_uint(f);
    return (u & 0x80000000u) ? ~u : (u | 0x80000000u);
}
__device__ __forceinline__ float dec_f32(unsigned u) {
    return (u & 0x80000000u) ? __uint_as_float(u & 0x7fffffffu)
                             : __uint_as_float(~u);
}
// fp32 -> bf16 bits, round-to-nearest-even
__device__ __forceinline__ short f2bf(float f) {
    unsigned u = __float_as_uint(f);
    u = u + 0x7fffu + ((u >> 16) & 1u);
    return (short)(u >> 16);
}

// Fragment-native global layout: element (row, k) with g16=row/16, r=row%16,
// kk=k/32, q=(k%32)/8, e=k%8 lives at  g16*2048 + kk*512 + q*128 + r*8 + e.
// A wave's fragment load for (g16, kk) is base + lane*8 shorts = 64 lanes x
// 16 B CONTIGUOUS (fixes R5's 256B-stride scatter: 64 cache lines -> 16).

// ---- kernel 1: prepass ------------------------------------------------------
// grid 512 x 256. Thread h: row = h/16, part p = h%16 -> (kk=p/4, q=p%4),
// i.e. elements k in [kk*32+q*8, +8): two consecutive float4 loads (32 B,
// coalesced), one 16 B store. Also exact fp32 sq1/sq2/posd (16-lane shuffle
// reduce) and all inits (rowmin, cnt, out).
__global__ void prep_kernel(const float* __restrict__ z1, const float* __restrict__ z2,
                            short* __restrict__ z1b, short* __restrict__ z2b,
                            float* __restrict__ sq1, float* __restrict__ sq2,
                            float* __restrict__ posd, unsigned* __restrict__ rowmin,
                            unsigned* __restrict__ cnt, float* __restrict__ out) {
    int h = blockIdx.x * 256 + threadIdx.x;     // 0 .. n*16-1
    int row = h >> 4, p = h & 15;
    int kk = p >> 2, q = p & 3;
    int f0 = row * 32 + kk * 8 + q * 2;         // first float4 index
    float4 fa0 = ((const float4*)z1)[f0], fa1 = ((const float4*)z1)[f0 + 1];
    float4 fb0 = ((const float4*)z2)[f0], fb1 = ((const float4*)z2)[f0 + 1];
    short8 sa = { f2bf(fa0.x), f2bf(fa0.y), f2bf(fa0.z), f2bf(fa0.w),
                  f2bf(fa1.x), f2bf(fa1.y), f2bf(fa1.z), f2bf(fa1.w) };
    short8 sb = { f2bf(fb0.x), f2bf(fb0.y), f2bf(fb0.z), f2bf(fb0.w),
                  f2bf(fb1.x), f2bf(fb1.y), f2bf(fb1.z), f2bf(fb1.w) };
    size_t off = (size_t)(row >> 4) * 2048 + kk * 512 + q * 128 + (row & 15) * 8;
    *(short8*)&z1b[off] = sa;
    *(short8*)&z2b[off] = sb;

    float s1 = fa0.x*fa0.x + fa0.y*fa0.y + fa0.z*fa0.z + fa0.w*fa0.w
             + fa1.x*fa1.x + fa1.y*fa1.y + fa1.z*fa1.z + fa1.w*fa1.w;
    float s2 = fb0.x*fb0.x + fb0.y*fb0.y + fb0.z*fb0.z + fb0.w*fb0.w
             + fb1.x*fb1.x + fb1.y*fb1.y + fb1.z*fb1.z + fb1.w*fb1.w;
    float dx0 = fa0.x-fb0.x, dy0 = fa0.y-fb0.y, dz0 = fa0.z-fb0.z, dw0 = fa0.w-fb0.w;
    float dx1 = fa1.x-fb1.x, dy1 = fa1.y-fb1.y, dz1 = fa1.z-fb1.z, dw1 = fa1.w-fb1.w;
    float p2 = dx0*dx0 + dy0*dy0 + dz0*dz0 + dw0*dw0
             + dx1*dx1 + dy1*dy1 + dz1*dz1 + dw1*dw1;
    #pragma unroll
    for (int m = 8; m >= 1; m >>= 1) {          // 16 threads per row
        s1 += __shfl_xor(s1, m);
        s2 += __shfl_xor(s2, m);
        p2 += __shfl_xor(p2, m);
    }
    if (p == 0) { sq1[row] = s1; sq2[row] = s2; posd[row] = sqrtf(p2); }

    if (threadIdx.x < 16) rowmin[blockIdx.x * 16 + threadIdx.x] = 0xFFFFFFFFu;
    if (blockIdx.x == 0) {
        if (threadIdx.x < 32) cnt[threadIdx.x] = 0u;
        if (threadIdx.x == 0) out[0] = 0.0f;
    }
}

// ---- kernel 2: barrier-free register GEMM + row-min + fused loss ------------
// grid (16, 32): rg = 256-row group (4 waves x 64 rows), cgi = 512-col group
// (16 tiles of 32 cols). 512 blocks = 2/CU. No LDS staging, no __syncthreads
// in the loop; all fragment loads are coalesced 1 KB wave loads.
__global__ __launch_bounds__(256, 2)
void gemm_min_kernel(const short* __restrict__ z1b, const short* __restrict__ z2b,
                     const float* __restrict__ sq1, const float* __restrict__ sq2,
                     const float* __restrict__ posd,
                     unsigned* __restrict__ rowmin, unsigned* __restrict__ cnt,
                     float* __restrict__ out, int n)
{
    __shared__ float lsum[4];
    __shared__ int   fin_s;

    const int rg = blockIdx.y, cgi = blockIdx.x;
    const int tid = threadIdx.x, w = tid >> 6, lane = tid & 63;
    const int quad = lane >> 4, l15 = lane & 15;
    const int rowbase = rg * 256 + w * 64;      // this wave's 64 rows
    const int colorig = cgi * 512;

    // persistent A fragments: af[sm][kk] = A[m = l15 + sm*16 (+rowbase)][kk*32+quad*8 ..+7]
    short8 af[4][4];
    #pragma unroll
    for (int sm = 0; sm < 4; ++sm) {
        const short* pa = z1b + (size_t)(rg * 16 + w * 4 + sm) * 2048 + lane * 8;
        #pragma unroll
        for (int kk = 0; kk < 4; ++kk)
            af[sm][kk] = *(const short8*)(pa + kk * 512);
    }

    float vmin[4][4];
    #pragma unroll
    for (int sm = 0; sm < 4; ++sm)
        #pragma unroll
        for (int reg = 0; reg < 4; ++reg)
            vmin[sm][reg] = 3.0e38f;

    short8 bb[2][2][4];                         // [buf][sn][kk] register dbuf
    #pragma unroll
    for (int sn = 0; sn < 2; ++sn) {
        const short* pb = z2b + (size_t)(cgi * 32 + sn) * 2048 + lane * 8;
        #pragma unroll
        for (int kk = 0; kk < 4; ++kk)
            bb[0][sn][kk] = *(const short8*)(pb + kk * 512);
    }

    #pragma unroll
    for (int t = 0; t < 16; ++t) {
        if (t < 15) {                           // prefetch next 32-col tile
            #pragma unroll
            for (int sn = 0; sn < 2; ++sn) {
                const short* pb = z2b + (size_t)(cgi * 32 + (t + 1) * 2 + sn) * 2048 + lane * 8;
                #pragma unroll
                for (int kk = 0; kk < 4; ++kk)
                    bb[(t + 1) & 1][sn][kk] = *(const short8*)(pb + kk * 512);
            }
        }
        const int colbase = colorig + t * 32;
        float s2v0 = sq2[colbase + l15];
        float s2v1 = sq2[colbase + 16 + l15];

        floatx4 acc[4][2];
        #pragma unroll
        for (int sm = 0; sm < 4; ++sm)
            #pragma unroll
            for (int sn = 0; sn < 2; ++sn)
                acc[sm][sn] = (floatx4)0.0f;

        #pragma unroll
        for (int kk = 0; kk < 4; ++kk)
            #pragma unroll
            for (int sm = 0; sm < 4; ++sm)
                #pragma unroll
                for (int sn = 0; sn < 2; ++sn)
                    acc[sm][sn] = __builtin_amdgcn_mfma_f32_16x16x32_bf16(
                        af[sm][kk], bb[t & 1][sn][kk], acc[sm][sn], 0, 0, 0);

        // fold v = sq2[j] - 2*dot into row-min; diagonal only if tiles overlap
        if (colbase < rowbase + 64 && rowbase < colbase + 32) {
            #pragma unroll
            for (int sm = 0; sm < 4; ++sm)
                #pragma unroll
                for (int reg = 0; reg < 4; ++reg) {
                    int gi = rowbase + sm * 16 + quad * 4 + reg;  // C/D: col=l15, row=quad*4+reg
                    float v0 = fmaf(-2.0f, acc[sm][0][reg], s2v0);
                    float v1 = fmaf(-2.0f, acc[sm][1][reg], s2v1);
                    v0 = (gi == colbase + l15)      ? 3.0e38f : v0;
                    v1 = (gi == colbase + 16 + l15) ? 3.0e38f : v1;
                    vmin[sm][reg] = fminf(vmin[sm][reg], fminf(v0, v1));
                }
        } else {
            #pragma unroll
            for (int sm = 0; sm < 4; ++sm)
                #pragma unroll
                for (int reg = 0; reg < 4; ++reg) {
                    float v0 = fmaf(-2.0f, acc[sm][0][reg], s2v0);
                    float v1 = fmaf(-2.0f, acc[sm][1][reg], s2v1);
                    vmin[sm][reg] = fminf(vmin[sm][reg], fminf(v0, v1));
                }
        }
    }

    // min across each quad's 16 lanes, one atomicMin per row
    #pragma unroll
    for (int sm = 0; sm < 4; ++sm)
        #pragma unroll
        for (int reg = 0; reg < 4; ++reg) {
            float vm = vmin[sm][reg];
            #pragma unroll
            for (int m = 8; m >= 1; m >>= 1)
                vm = fminf(vm, __shfl_xor(vm, m));
            if (l15 == 0)
                atomicMin(&rowmin[rowbase + sm * 16 + quad * 4 + reg], enc_f32(vm));
        }

    __syncthreads();
    if (tid == 0) {
        __threadfence();    // release: this block's mins visible before bump
        fin_s = (atomicAdd(&cnt[rg], 1u) == 15u);
    }
    __syncthreads();
    if (!fin_s) return;
    __threadfence();        // acquire: see all 16 blocks' mins

    // fused loss for rows [rg*256, rg*256+256): thread = one row
    {
        int i = rg * 256 + tid;
        unsigned rm = atomicMin(&rowmin[i], 0xFFFFFFFFu);   // coherent forced read
        float hard = sqrtf(fmaxf(sq1[i] + dec_f32(rm), 0.0f));
        float l = fmaxf(posd[i] - hard + MARGIN, 0.0f);
        #pragma unroll
        for (int m = 32; m >= 1; m >>= 1) l += __shfl_xor(l, m);
        if (lane == 0) lsum[w] = l;
    }
    __syncthreads();
    if (tid == 0)
        atomicAdd(out, (lsum[0] + lsum[1] + lsum[2] + lsum[3]) / (float)n);
}

// ---- launch -----------------------------------------------------------------
extern "C" void kernel_launch(void* const* d_in, const int* in_sizes, int n_in,
                              void* d_out, int out_size, void* d_ws, size_t ws_size,
                              hipStream_t stream) {
    const float* z1 = (const float*)d_in[0];
    const float* z2 = (const float*)d_in[1];
    const int n = in_sizes[0] / 128;            // 8192

    char* ws = (char*)d_ws;
    short*    z1b    = (short*)ws;                                     // 2 MB
    short*    z2b    = (short*)(ws + (size_t)n * 128 * 2);             // 2 MB
    float*    sq1    = (float*)(ws + (size_t)n * 128 * 4);             // 32 KB
    float*    sq2    = (float*)(ws + (size_t)n * 128 * 4 + n * 4);     // 32 KB
    float*    posd   = (float*)(ws + (size_t)n * 128 * 4 + n * 8);     // 32 KB
    unsigned* rowmin = (unsigned*)(ws + (size_t)n * 128 * 4 + n * 12); // 32 KB
    unsigned* cnt    = (unsigned*)(ws + (size_t)n * 128 * 4 + n * 16); // 128 B
    float*    out    = (float*)d_out;

    prep_kernel<<<n / 16, 256, 0, stream>>>(z1, z2, z1b, z2b, sq1, sq2, posd,
                                            rowmin, cnt, out);
    dim3 grid(16, n / 256);                     // (colgroups, rowgroups)
    gemm_min_kernel<<<grid, 256, 0, stream>>>(z1b, z2b, sq1, sq2, posd,
                                              rowmin, cnt, out, n);
}